// Round 1
// baseline (252.770 us; speedup 1.0000x reference)
//
#include <hip/hip_runtime.h>

// PyramidROIAlign: B=2, N=1000, C=256, pool 7x7.
// fmaps: P2 [B,256,256,C], P3 [B,128,128,C], P4 [B,64,64,C], P5 [B,32,32,C], f32.
// Output [B,N,7,7,C] f32.
//
// One 64-lane wave per (box, py) ROW (7 pool cells). Box/level/y setup is
// computed once per wave (scalarized via readfirstlane) and amortized over
// the 7 px positions; the unrolled px loop exposes 28 independent corner
// loads for memory-level parallelism. Lane handles 4 channels (float4).
// Output stores are nontemporal so the 100 MB write stream doesn't evict
// fmap corner lines from L2 (corners are reused heavily within a box).

#define POOL 7
#define CCH 256

typedef float f32x4 __attribute__((ext_vector_type(4)));

__global__ __launch_bounds__(256) void roi_align_row_kernel(
    const float* __restrict__ boxes,   // [B*N, 4] y1,x1,y2,x2
    const float* __restrict__ ish,     // [2]
    const float* __restrict__ P2,
    const float* __restrict__ P3,
    const float* __restrict__ P4,
    const float* __restrict__ P5,
    float* __restrict__ out,           // [B*N, 7, 7, C]
    int n_rows, int N)
{
    int row = blockIdx.x * 4 + (threadIdx.x >> 6);
    if (row >= n_rows) return;
    // Uniform within the wave; readfirstlane lets the compiler prove it and
    // scalarize the box loads + address arithmetic below.
    row = __builtin_amdgcn_readfirstlane(row);
    const int lane = threadIdx.x & 63;
    const int c = lane * 4;

    int py = row % POOL;
    int n  = row / POOL;          // flat box index in [0, B*N)
    int b  = n / N;               // batch index

    float y1 = boxes[n * 4 + 0];
    float x1 = boxes[n * 4 + 1];
    float y2 = boxes[n * 4 + 2];
    float x2 = boxes[n * 4 + 3];
    float h = y2 - y1;
    float w = x2 - x1;

    // compute_roi_level — replicate reference expression order exactly.
    float area = ish[0] * ish[1];
    float lvl  = log2f(sqrtf(h * w) / (224.0f / sqrtf(area)));
    float Lf   = fminf(5.0f, fmaxf(2.0f, 4.0f + rintf(lvl)));  // rintf = round-half-even
    int   L    = (int)Lf;

    const float* fmap;
    int H;
    if (L == 2)      { fmap = P2; H = 256; }
    else if (L == 3) { fmap = P3; H = 128; }
    else if (L == 4) { fmap = P4; H = 64;  }
    else             { fmap = P5; H = 32;  }
    const int W = H;

    // y setup — once per wave, amortized over 7 px cells.
    float gy   = (float)py / (float)(POOL - 1);
    float in_y = (y1 + h * gy) * (float)(H - 1);
    float y0f  = floorf(in_y);
    float wy   = in_y - y0f;
    int y0  = min(max((int)y0f, 0), H - 1);
    int y1i = min(y0 + 1, H - 1);

    size_t base = (size_t)b * H * W * CCH;
    const float* rowT = fmap + base + (size_t)y0  * W * CCH + c;
    const float* rowB = fmap + base + (size_t)y1i * W * CCH + c;

    float* orow = out + (size_t)row * POOL * CCH + c;

    #pragma unroll
    for (int px = 0; px < POOL; ++px) {
        float gx   = (float)px / (float)(POOL - 1);   // compile-time constant per unrolled iter
        float in_x = (x1 + w * gx) * (float)(W - 1);
        float x0f  = floorf(in_x);
        float wx   = in_x - x0f;
        int x0  = min(max((int)x0f, 0), W - 1);
        int x1i = min(x0 + 1, W - 1);
        int o0 = x0  * CCH;
        int o1 = x1i * CCH;

        f32x4 tl = *(const f32x4*)(rowT + o0);
        f32x4 tr = *(const f32x4*)(rowT + o1);
        f32x4 bl = *(const f32x4*)(rowB + o0);
        f32x4 br = *(const f32x4*)(rowB + o1);

        f32x4 top = tl + (tr - tl) * wx;
        f32x4 bot = bl + (br - bl) * wx;
        f32x4 o   = top + (bot - top) * wy;

        __builtin_nontemporal_store(o, (f32x4*)(orow + px * CCH));
    }
}

extern "C" void kernel_launch(void* const* d_in, const int* in_sizes, int n_in,
                              void* d_out, int out_size, void* d_ws, size_t ws_size,
                              hipStream_t stream)
{
    const float* boxes = (const float*)d_in[0];
    const float* ish   = (const float*)d_in[1];
    const float* P2    = (const float*)d_in[2];
    const float* P3    = (const float*)d_in[3];
    const float* P4    = (const float*)d_in[4];
    const float* P5    = (const float*)d_in[5];
    float* out = (float*)d_out;

    int total_boxes = in_sizes[0] / 4;                  // B*N = 2000
    int B = in_sizes[2] / (256 * 256 * CCH);            // P2 is [B,256,256,C]
    int N = total_boxes / B;
    int n_rows = total_boxes * POOL;                    // 14000 (one wave each)

    int blocks = (n_rows + 3) / 4;                      // 4 waves per 256-thread block
    roi_align_row_kernel<<<blocks, 256, 0, stream>>>(boxes, ish, P2, P3, P4, P5,
                                                     out, n_rows, N);
}